// Round 9
// baseline (813.708 us; speedup 1.0000x reference)
//
#include <hip/hip_runtime.h>
#include <math.h>

#define HWIMG 18432          // 96*192
#define W2 194               // padded width, pad=1
#define H2 98
#define NPX1 (H2 * W2)       // 19012 padded pixels, pad=1
#define W4 200               // padded width, pad=4
#define H4 104
#define NPX4 (H4 * W4)       // 20800 padded pixels, pad=4
#define NOUT (19 * 384 * 768)

typedef short bf16x8 __attribute__((ext_vector_type(8)));
typedef float f32x4 __attribute__((ext_vector_type(4)));

__device__ __forceinline__ ushort bf16r(float f) {
    union { float f; unsigned u; } a; a.f = f;
    unsigned u = a.u;
    return (ushort)((u + 0x7fffu + ((u >> 16) & 1u)) >> 16);
}
__device__ __forceinline__ float b2f(ushort u) {
    union { unsigned i; float f; } a; a.i = ((unsigned)u) << 16;
    return a.f;
}
__device__ __forceinline__ bf16x8 ld8(const ushort* p) {
    return *reinterpret_cast<const bf16x8*>(p);
}

// async global->LDS, 16B per lane. LDS dest: wave-uniform base + lane*16.
__device__ __forceinline__ void gld16(const ushort* g, ushort* l) {
    __builtin_amdgcn_global_load_lds(
        (const __attribute__((address_space(1))) unsigned int*)g,
        (__attribute__((address_space(3))) unsigned int*)l, 16, 0, 0);
}

#define MF16(a, b, c) __builtin_amdgcn_mfma_f32_16x16x32_bf16(a, b, c, 0, 0, 0)

// LDS bank-conflict swizzle on 16B slots: XOR byte bits [6:4] with bits [9:7].
__device__ __forceinline__ int swz(int L) { return L ^ (((L >> 7) & 7) << 4); }

// ===========================================================================
// Tiled activation layout: act[cb][px][c16]  (cb = ch/16, px in padded pad=1
// image, c16 = ch%16). Weights: wt[kb][tap][ocp][16].
// ===========================================================================

// NCHW f32 -> tiled bf16 (full padded range, borders zeroed). optional src-src2.
__global__ __launch_bounds__(256) void xform_t_k(const float* __restrict__ src,
                                                 const float* __restrict__ src2,
                                                 ushort* __restrict__ dst)
{
    const int px = blockIdx.x * 32 + (threadIdx.x & 31);
    const int c8 = (blockIdx.y * 8 + (threadIdx.x >> 5)) * 8;
    if (px >= NPX1) return;
    const int yP = px / W2, xP = px % W2;
    const int y = yP - 1, x = xP - 1;
    ushort v[8];
    if (y >= 0 && y < 96 && x >= 0 && x < 192) {
        const int p = y * 192 + x;
#pragma unroll
        for (int j = 0; j < 8; ++j) {
            float f = src[(size_t)(c8 + j) * HWIMG + p];
            if (src2) f -= src2[(size_t)(c8 + j) * HWIMG + p];
            v[j] = bf16r(f);
        }
    } else {
#pragma unroll
        for (int j = 0; j < 8; ++j) v[j] = 0;
    }
    *reinterpret_cast<uint4*>(dst + ((size_t)(c8 >> 4) * NPX1 + px) * 16 + (c8 & 15))
        = *reinterpret_cast<uint4*>(v);
}

// NCHW f32 -> padded NHWC bf16 (pad=4), for the propagation input only.
__global__ __launch_bounds__(256) void xform_nhwc_k(const float* __restrict__ src,
                                                    ushort* __restrict__ dst)
{
    const int px = blockIdx.x * 8 + (threadIdx.x >> 5);
    const int c8 = (threadIdx.x & 31) * 8;
    if (px >= NPX4) return;
    const int yP = px / W4, xP = px % W4;
    const int y = yP - 4, x = xP - 4;
    ushort v[8];
    if (y >= 0 && y < 96 && x >= 0 && x < 192) {
        const int p = y * 192 + x;
#pragma unroll
        for (int j = 0; j < 8; ++j) v[j] = bf16r(src[(size_t)(c8 + j) * HWIMG + p]);
    } else {
#pragma unroll
        for (int j = 0; j < 8; ++j) v[j] = 0;
    }
    *reinterpret_cast<uint4*>(dst + (size_t)px * 256 + c8) = *reinterpret_cast<uint4*>(v);
}

// Zero pad=1 border pixels of three 16-cb tiled buffers.
__global__ __launch_bounds__(256) void borderzero3_k(ushort* __restrict__ b0,
                                                     ushort* __restrict__ b1,
                                                     ushort* __restrict__ b2)
{
    ushort* buf = (blockIdx.y == 0) ? b0 : ((blockIdx.y == 1) ? b1 : b2);
    const int idx = blockIdx.x * 256 + threadIdx.x;
    if (idx >= 580 * 16) return;
    const int pi = idx % 580;
    const int cb = idx / 580;
    int pp;
    if (pi < 194) pp = pi;
    else if (pi < 388) pp = 97 * 194 + (pi - 194);
    else if (pi < 484) pp = (pi - 388 + 1) * 194;
    else pp = (pi - 484 + 1) * 194 + 193;
    uint4 z = {0, 0, 0, 0};
    ushort* p = buf + ((size_t)cb * NPX1 + pp) * 16;
    *reinterpret_cast<uint4*>(p) = z;
    *reinterpret_cast<uint4*>(p + 8) = z;
}

// ---------------------------------------------------------------------------
// Batched weight transform: OIHW f32 -> wt[kb][tap][ocp][16] bf16 + bias f32.
// ---------------------------------------------------------------------------
struct WtxJob {
    const float* w; const float* b; const float* g; const float* beta;
    int CoutR, Coutp, CinR0, kb0e, CinR1, KBt, ntaps, wtoff, biasoff;
};

__global__ __launch_bounds__(256) void wtx_multi_k(WtxJob J0, WtxJob J1, WtxJob J2,
                                                   WtxJob J3, WtxJob J4, WtxJob J5,
                                                   ushort* __restrict__ wt,
                                                   float* __restrict__ biasout)
{
    WtxJob J = J0;
    switch (blockIdx.y) {
        case 1: J = J1; break; case 2: J = J2; break; case 3: J = J3; break;
        case 4: J = J4; break; case 5: J = J5; break; default: break;
    }
    const int idx = blockIdx.x * 256 + threadIdx.x;
    const int total = J.ntaps * J.KBt * J.Coutp * 16;
    const int CinT = J.CinR0 + J.CinR1;
    if (idx < total) {
        const int c16 = idx & 15;
        const int oc = (idx >> 4) % J.Coutp;
        const int r2 = idx / (16 * J.Coutp);
        const int tap = r2 % J.ntaps;
        const int kbt = r2 / J.ntaps;
        const int k = kbt * 16 + c16;
        float val = 0.f;
        if (oc < J.CoutR) {
            int cit = -1;
            if (k < J.kb0e) { if (k < J.CinR0) cit = k; }
            else { const int k1 = k - J.kb0e; if (k1 < J.CinR1) cit = J.CinR0 + k1; }
            if (cit >= 0) {
                val = J.w[((size_t)oc * CinT + cit) * J.ntaps + tap];
                if (J.g) val *= J.g[oc];
            }
        }
        wt[J.wtoff + idx] = bf16r(val);
    } else if (idx < total + J.Coutp) {
        const int oc = idx - total;
        float v = 0.f;
        if (oc < J.CoutR) {
            v = J.b ? J.b[oc] : 0.f;
            if (J.g) v = v * J.g[oc] + J.beta[oc];
        }
        biasout[J.biasoff + oc] = v;
    }
}

// ---------------------------------------------------------------------------
// LDS-staged implicit-GEMM conv, 16x16x32 MFMA, 4x4 fragment tile per wave,
// STATIC double-buffered (A0/B0 vs A1/B1 distinct shared arrays so alias
// analysis keeps ds_reads independent of the in-flight global_load_lds; the
// syncthreads vmcnt(0) drain then waits on loads issued a full compute phase
// earlier -> hidden). K-step = 32 ch = 2 cb planes. Block = 128 thr = 2 waves;
// tile 128px x 64oc; wave 64px x 64oc (acc 16 x f32x4).
// grid.x = 144 * Coutp/64 (XCD-swizzled), grid.y = job.
// ---------------------------------------------------------------------------
struct ConvJob {
    const ushort* in0; const ushort* in1;
    int KB0, KB1;
    const ushort* wt;
    const float* bias;
    ushort* out;
    int CoutWr;            // writable channels (multiple of 16)
};

template<int NTAPS>
__device__ __forceinline__ void stage_kb(
    const ConvJob& J, int kb, int kbh, char* Ab, char* Bb,
    int y0, int x0, int ocb0, int Coutp, int tid, int b_r, int b_h8, int wu)
{
    constexpr int AROWS = (NTAPS == 9) ? 4 : 2;
    constexpr int AW = (NTAPS == 9) ? 66 : 64;
    constexpr int ASLOTS = AROWS * AW * 2;            // 16B slots per plane
    const ushort* plane = (kb < J.KB0)
        ? (J.in0 + (size_t)kb * (NPX1 * 16))
        : (J.in1 + (size_t)(kb - J.KB0) * (NPX1 * 16));
    // A-halo: linear LDS dest, inverse-swizzled global source
#pragma unroll
    for (int i = 0; i < (ASLOTS + 127) / 128; ++i) {
        const int f16 = i * 128 + tid;
        if ((ASLOTS % 128 == 0) || (f16 < ASLOTS)) {
            const int L = swz(f16 * 16);
            const int e = L >> 5;
            const int h8 = ((L >> 4) & 1) * 8;
            const int r = e / AW;
            const int xx = e - r * AW;
            const int px = (NTAPS == 9)
                ? (y0 - 1 + r) * W2 + (x0 - 1 + xx)
                : (y0 + r) * W2 + (x0 + xx);
            gld16(plane + (size_t)px * 16 + h8,
                  (ushort*)(Ab + __builtin_amdgcn_readfirstlane((f16 & ~63) * 16)));
        }
    }
    // B: region (tap*2 + kbh) of 2KB ([64oc][16ch])
    const ushort* wsrc = J.wt + ((size_t)kb * NTAPS * Coutp + ocb0 + b_r) * 16 + b_h8;
#pragma unroll
    for (int t = 0; t < NTAPS; ++t) {
        gld16(wsrc + (size_t)t * Coutp * 16, (ushort*)(Bb + (t * 2 + kbh) * 2048 + wu));
    }
}

// stage one K-step (2 cb planes) into the given buffer pair
template<int NTAPS>
__device__ __forceinline__ void stage_step(
    const ConvJob& J, int st, char* Ab, char* Bb, int APLANE,
    int y0, int x0, int ocb0, int Coutp, int tid, int b_r, int b_h8, int wu)
{
    stage_kb<NTAPS>(J, 2 * st,     0, Ab,          Bb, y0, x0, ocb0, Coutp, tid, b_r, b_h8, wu);
    stage_kb<NTAPS>(J, 2 * st + 1, 1, Ab + APLANE, Bb, y0, x0, ocb0, Coutp, tid, b_r, b_h8, wu);
}

template<int NTAPS>
__device__ __forceinline__ void compute_step(
    f32x4 acc[4][4], const char* Ab, const char* Bb, int APLANE,
    int wm, int l15, int kh16, int pl)
{
    constexpr int AW = (NTAPS == 9) ? 66 : 64;
    const char* Ap = Ab + pl * APLANE;
#pragma unroll
    for (int t = 0; t < NTAPS; ++t) {
        const int rowb = (NTAPS == 9) ? ((wm + t / 3) * AW + (t % 3)) : (wm * AW);
        const char* Bp = Bb + (t * 2 + pl) * 2048;
        bf16x8 a[4], b[4];
#pragma unroll
        for (int q = 0; q < 4; ++q) {
            const int la = (rowb + q * 16 + l15) * 32 + kh16;
            a[q] = ld8((const ushort*)(Ap + swz(la)));
            const int lb = (q * 16 + l15) * 32 + kh16;
            b[q] = ld8((const ushort*)(Bp + swz(lb)));
        }
#pragma unroll
        for (int i = 0; i < 4; ++i)
#pragma unroll
            for (int j = 0; j < 4; ++j)
                acc[i][j] = MF16(a[i], b[j], acc[i][j]);
    }
}

template<int NTAPS>
__global__ __launch_bounds__(128) void conv_lds_k(ConvJob j0, ConvJob j1, ConvJob j2,
                                                  int Coutp)
{
    constexpr int AROWS = (NTAPS == 9) ? 4 : 2;
    constexpr int AW = (NTAPS == 9) ? 66 : 64;
    constexpr int APLANE = AROWS * AW * 32;           // 8448 or 4096 B
    // STATIC double buffers (distinct arrays -> no forced vmcnt before ds_read)
    __shared__ __align__(1024) char A0[2 * APLANE];
    __shared__ __align__(1024) char A1[2 * APLANE];
    __shared__ __align__(1024) char B0[NTAPS * 2 * 2048];
    __shared__ __align__(1024) char B1[NTAPS * 2 * 2048];

    ConvJob J = j0;
    if (blockIdx.y == 1) J = j1;
    else if (blockIdx.y == 2) J = j2;

    const int nblk = gridDim.x;
    const int cpx = nblk >> 3;                        // nblk % 8 == 0
    const int sw = ((int)blockIdx.x & 7) * cpx + ((int)blockIdx.x >> 3);
    const int pt = sw % 144;
    const int ocb0 = (sw / 144) * 64;
    const int y0 = (pt / 3) * 2 + 1;
    const int x0 = (pt % 3) * 64 + 1;

    const int tid = threadIdx.x;                      // 0..127
    const int lane = tid & 63;
    const int wm = tid >> 6;                          // wave id = px row
    const int l15 = lane & 15;
    const int kh16 = ((lane >> 4) & 1) * 16;          // 16B k-half within 32B row
    const int pl = lane >> 5;                         // kb-plane select (k>=16)

    // staging source indices: invert the LDS swizzle (within a 2KB B region)
    const int bl = swz(tid * 16);
    const int b_r = bl >> 5;
    const int b_h8 = ((bl >> 4) & 1) * 8;
    const int wu = __builtin_amdgcn_readfirstlane((tid & ~63) * 16);

    const int KBtot = J.KB0 + J.KB1;                  // even
    const int nsteps = KBtot >> 1;                    // 8, 10, or 16 -> even

    f32x4 acc[4][4] = {};

    stage_step<NTAPS>(J, 0, A0, B0, APLANE, y0, x0, ocb0, Coutp, tid, b_r, b_h8, wu);
    __syncthreads();

    for (int s = 0; s < nsteps; s += 2) {
        // phase 1: stage step s+1 into S1 while computing step s from S0
        stage_step<NTAPS>(J, s + 1, A1, B1, APLANE, y0, x0, ocb0, Coutp, tid, b_r, b_h8, wu);
        __builtin_amdgcn_sched_barrier(0);
        compute_step<NTAPS>(acc, A0, B0, APLANE, wm, l15, kh16, pl);
        __syncthreads();   // drains S1 stage (issued one compute phase ago)
        // phase 2: stage step s+2 into S0 while computing step s+1 from S1
        const int sn = (s + 2 < nsteps) ? (s + 2) : (nsteps - 1);  // clamped (redundant ok)
        stage_step<NTAPS>(J, sn, A0, B0, APLANE, y0, x0, ocb0, Coutp, tid, b_r, b_h8, wu);
        __builtin_amdgcn_sched_barrier(0);
        compute_step<NTAPS>(acc, A1, B1, APLANE, wm, l15, kh16, pl);
        __syncthreads();
    }

    // ---- epilogue: 16x16 C/D map col=lane&15 (oc), row=(lane>>4)*4+r (px) ----
    const int pxbase = (y0 + wm) * W2 + x0;
    const int r4 = (lane >> 4) * 4;
#pragma unroll
    for (int qo = 0; qo < 4; ++qo) {
        if (ocb0 + qo * 16 + 16 > J.CoutWr) continue;  // wave-uniform
        const int oc = ocb0 + qo * 16 + l15;
        const float bs = J.bias[oc];
        const size_t obase = (size_t)(oc >> 4) * ((size_t)NPX1 * 16) + (oc & 15);
#pragma unroll
        for (int qp = 0; qp < 4; ++qp) {
            const int pp = pxbase + qp * 16 + r4;
#pragma unroll
            for (int r = 0; r < 4; ++r)
                J.out[obase + (size_t)(pp + r) * 16] = bf16r(acc[qp][qo][r] + bs);
        }
    }
}

// ---------------------------------------------------------------------------
// Softmax over 81 channels (tiled layout), in place, interior pixels.
// ---------------------------------------------------------------------------
__global__ __launch_bounds__(256) void softmax81_k(ushort* __restrict__ t)
{
    const int p = blockIdx.x * 256 + threadIdx.x;
    if (p >= HWIMG) return;
    const int y = p / 192, x = p % 192;
    const size_t pp = (size_t)(y + 1) * W2 + (x + 1);
    float v[81];
    float m = -1e30f;
#pragma unroll
    for (int k = 0; k < 81; ++k) {
        v[k] = b2f(t[((size_t)(k >> 4) * NPX1 + pp) * 16 + (k & 15)]);
        m = fmaxf(m, v[k]);
    }
    float s = 0.f;
#pragma unroll
    for (int k = 0; k < 81; ++k) { v[k] = __expf(v[k] - m); s += v[k]; }
    const float inv = 1.f / s;
#pragma unroll
    for (int k = 0; k < 81; ++k)
        t[((size_t)(k >> 4) * NPX1 + pp) * 16 + (k & 15)] = bf16r(v[k] * inv);
}

// ---------------------------------------------------------------------------
// Propagation: out[px][c] = sum_k deep[y+dy][x+dx][c] * ker[px][k]
// deep: pad4 NHWC bf16; ker: tiled (6 cb used); out: tiled, FULL write.
// ---------------------------------------------------------------------------
__global__ __launch_bounds__(256) void prop_k(const ushort* __restrict__ deep,
                                              const ushort* __restrict__ ker,
                                              ushort* __restrict__ out)
{
    __shared__ float kl[8][81];
    const int pxb = blockIdx.x * 8;
    const int t = threadIdx.x;
    for (int i = t; i < 8 * 81; i += 256) {
        const int pp = pxb + i / 81, k = i % 81;
        float kv = 0.f;
        if (pp < NPX1) {
            const int yP = pp / W2, xP = pp % W2;
            if (yP >= 1 && yP <= 96 && xP >= 1 && xP <= 192)
                kv = b2f(ker[((size_t)(k >> 4) * NPX1 + pp) * 16 + (k & 15)]);
        }
        kl[i / 81][k] = kv;
    }
    __syncthreads();
    const int pi = t >> 5;
    const int c8 = (t & 31) * 8;
    const int pp = pxb + pi;
    if (pp >= NPX1) return;
    const int yP = pp / W2, xP = pp % W2;
    ushort* op = out + ((size_t)(c8 >> 4) * NPX1 + pp) * 16 + (c8 & 15);
    if (yP < 1 || yP > 96 || xP < 1 || xP > 192) {
        uint4 z = {0, 0, 0, 0};
        *reinterpret_cast<uint4*>(op) = z;
        return;
    }
    const int y = yP - 1, x = xP - 1;
    float acc[8];
#pragma unroll
    for (int j = 0; j < 8; ++j) acc[j] = 0.f;
    const ushort* dbase = deep + ((size_t)(y + 4) * W4 + (x + 4)) * 256 + c8;
#pragma unroll
    for (int k = 0; k < 81; ++k) {
        const int dy = k / 9 - 4, dx = k % 9 - 4;
        const float kv = kl[pi][k];
        bf16x8 d = ld8(dbase + (ptrdiff_t)(dy * W4 + dx) * 256);
#pragma unroll
        for (int j = 0; j < 8; ++j) acc[j] += b2f((ushort)d[j]) * kv;
    }
    ushort v[8];
#pragma unroll
    for (int j = 0; j < 8; ++j) v[j] = bf16r(acc[j]);
    *reinterpret_cast<uint4*>(op) = *reinterpret_cast<uint4*>(v);
}

// ---------------------------------------------------------------------------
// Per-row-chunk channel sums (tiled input): partial[(y*4+bx)][c], 48 px each
// ---------------------------------------------------------------------------
__global__ __launch_bounds__(256) void rowsum_k(const ushort* __restrict__ t,
                                                float* __restrict__ partial)
{
    const int y = blockIdx.x >> 2;
    const int bx = blockIdx.x & 3;
    const int c = threadIdx.x;
    const size_t base = ((size_t)(c >> 4) * NPX1 + (size_t)(y + 1) * W2 + 1 + bx * 48) * 16
                      + (c & 15);
    float s = 0.f;
    for (int x = 0; x < 48; ++x) s += b2f(t[base + (size_t)x * 16]);
    partial[(size_t)blockIdx.x * 256 + c] = s;
}

__global__ __launch_bounds__(256) void dev_k(const float* __restrict__ partial,
                                             const float* __restrict__ fcw,
                                             const float* __restrict__ fcb,
                                             float* __restrict__ o)
{
    __shared__ float buf[256];
    const int c = threadIdx.x;
    float s = 0.f;
    for (int i = 0; i < 384; ++i) s += partial[(size_t)i * 256 + c];
    buf[c] = s * fcw[c];
    __syncthreads();
    for (int st = 128; st > 0; st >>= 1) {
        if (c < st) buf[c] += buf[c + st];
        __syncthreads();
    }
    if (c == 0) o[0] = buf[0] * (1.f / (float)HWIMG) + fcb[0];
}

// ---------------------------------------------------------------------------
// 4x bilinear upsample from tiled bf16 (19 ch used) -> f32 NCHW
// ---------------------------------------------------------------------------
__global__ __launch_bounds__(256) void upsample_k(const ushort* __restrict__ in,
                                                  float* __restrict__ outp)
{
    const int idx = blockIdx.x * 256 + threadIdx.x;
    if (idx >= NOUT) return;
    const int ox = idx % 768;
    const int t = idx / 768;
    const int oy = t % 384;
    const int c = t / 384;

    const float fx = (ox + 0.5f) * 0.25f - 0.5f;
    const float fy = (oy + 0.5f) * 0.25f - 0.5f;
    const int x0 = (int)floorf(fx);
    const int y0 = (int)floorf(fy);
    const float wx = fx - (float)x0;
    const float wy = fy - (float)y0;
    const int x0c = min(max(x0, 0), 191), x1c = min(max(x0 + 1, 0), 191);
    const int y0c = min(max(y0, 0), 95), y1c = min(max(y0 + 1, 0), 95);

    const size_t cb = (size_t)(c >> 4) * NPX1;
    const int c16 = c & 15;
    const float v00 = b2f(in[(cb + (size_t)(y0c + 1) * W2 + (x0c + 1)) * 16 + c16]);
    const float v01 = b2f(in[(cb + (size_t)(y0c + 1) * W2 + (x1c + 1)) * 16 + c16]);
    const float v10 = b2f(in[(cb + (size_t)(y1c + 1) * W2 + (x0c + 1)) * 16 + c16]);
    const float v11 = b2f(in[(cb + (size_t)(y1c + 1) * W2 + (x1c + 1)) * 16 + c16]);
    outp[idx] = (1.f - wy) * ((1.f - wx) * v00 + wx * v01)
              + wy * ((1.f - wx) * v10 + wx * v11);
}

// ---------------------------------------------------------------------------
extern "C" void kernel_launch(void* const* d_in, const int* in_sizes, int n_in,
                              void* d_out, int out_size, void* d_ws, size_t ws_size,
                              hipStream_t stream)
{
    const float* f1_deep = (const float*)d_in[0];
    const float* f1_low  = (const float*)d_in[1];
    const float* f2_low  = (const float*)d_in[2];
    const float* wp_c1_w = (const float*)d_in[3];
    const float* wp_c1_b = (const float*)d_in[4];
    const float* wp_c2_w = (const float*)d_in[5];
    const float* wp_c2_b = (const float*)d_in[6];
    const float* wp_fc_w = (const float*)d_in[7];
    const float* wp_fc_b = (const float*)d_in[8];
    const float* sch_c1_w = (const float*)d_in[9];
    const float* sch_c2_w = (const float*)d_in[11];
    const float* sch_c2_b = (const float*)d_in[12];
    const float* sch_fc_w = (const float*)d_in[13];
    const float* sch_fc_b = (const float*)d_in[14];
    const float* ad_c1_w = (const float*)d_in[15];
    const float* ad_c1_b = (const float*)d_in[16];
    const float* ad_c2_w = (const float*)d_in[17];
    const float* ad_c2_b = (const float*)d_in[18];
    const float* ad_c3_w = (const float*)d_in[19];
    const float* ad_c3_b = (const float*)d_in[20];
    const float* rc_w    = (const float*)d_in[21];
    const float* rc_b    = (const float*)d_in[22];
    const float* rc_g    = (const float*)d_in[23];
    const float* rc_beta = (const float*)d_in[24];
    const float* lc1_w   = (const float*)d_in[25];
    const float* lc1_b   = (const float*)d_in[26];
    const float* lc1_g   = (const float*)d_in[27];
    const float* lc1_beta= (const float*)d_in[28];
    const float* lc2_w   = (const float*)d_in[29];
    const float* lc2_b   = (const float*)d_in[30];
    const float* lc2_g   = (const float*)d_in[31];
    const float* lc2_beta= (const float*)d_in[32];
    const float* lc3_w   = (const float*)d_in[33];
    const float* lc3_b   = (const float*)d_in[34];

    float* out = (float*)d_out;
    ushort* ws0 = (ushort*)d_ws;

    const size_t CBBe  = (size_t)NPX1 * 256;   // elems of one 16-cb tiled buffer
    const size_t BUF0e = (size_t)NPX4 * 256;   // pad4 NHWC deep buffer elems

    ushort* Bb = ws0 + BUF0e;            // slot B
    ushort* Cb = Bb + CBBe;              // slot C
    ushort* Db = Cb + CBBe;              // slot D
    ushort* Eb = Db + CBBe;              // slot E
    ushort* Fb = Eb + CBBe;              // slot F
    ushort* WT = Fb + CBBe;              // weights: 3,719,168 elems
    float* BIAS = (float*)(WT + 3719168);
    float* PART = (float*)ws0;           // lives only step 6 (ws0 free there)
    ushort* L48 = Eb + 6 * (size_t)NPX1 * 16;   // cb6-9 of slot E

    const dim3 b256(256), b128(128);

    // 1. input transforms (full writes incl. zero borders)
    xform_t_k<<<dim3(595, 4), b256, 0, stream>>>(f1_low, nullptr, Bb);
    xform_t_k<<<dim3(595, 4), b256, 0, stream>>>(f2_low, nullptr, Cb);
    xform_t_k<<<dim3(595, 4), b256, 0, stream>>>(f1_low, f2_low, Db);
    // 2. zero borders of conv-output slots that get halo-read (stay zero after)
    borderzero3_k<<<dim3(37, 3), b256, 0, stream>>>(ws0, Eb, Fb);

    // 3. weight transforms, phase 1
    {
        WtxJob w0 = {wp_c1_w, wp_c1_b, nullptr, nullptr, 256, 256, 256, 256, 0, 16, 9, 0, 0};
        WtxJob w1 = {sch_c1_w, nullptr, nullptr, nullptr, 256, 256, 256, 256, 0, 16, 9, 589824, 256};
        WtxJob w2 = {wp_c2_w, wp_c2_b, nullptr, nullptr, 256, 256, 256, 256, 256, 32, 9, 1179648, 512};
        WtxJob w3 = {sch_c2_w, sch_c2_b, nullptr, nullptr, 256, 256, 256, 256, 0, 16, 9, 2359296, 768};
        WtxJob w4 = {wp_fc_w, wp_fc_b, nullptr, nullptr, 81, 128, 256, 256, 0, 16, 1, 2949120, 1024};
        WtxJob w5 = {rc_w, rc_b, rc_g, rc_beta, 48, 128, 256, 256, 0, 16, 1, 2981888, 1280};
        wtx_multi_k<<<dim3(4610, 6), b256, 0, stream>>>(w0, w1, w2, w3, w4, w5, WT, BIAS);
    }

    // 4. batch A: wp_c1(F1)->E, wp_c1(F2)->F, sch_c1(DIFF)->SCH1(ws0)
    {
        ConvJob a0 = {Bb, Bb, 16, 0, WT, BIAS, Eb, 256};
        ConvJob a1 = {Cb, Cb, 16, 0, WT, BIAS, Fb, 256};
        ConvJob a2 = {Db, Db, 16, 0, WT + 589824, BIAS + 256, ws0, 256};
        conv_lds_k<9><<<dim3(576, 3), b128, 0, stream>>>(a0, a1, a2, 256);
    }
    // 5. batch B: wp_c2(E,F)->D ; sch_c2(SCH1)->B
    {
        ConvJob a0 = {Eb, Fb, 16, 16, WT + 1179648, BIAS + 512, Db, 256};
        ConvJob a1 = {ws0, ws0, 16, 0, WT + 2359296, BIAS + 768, Bb, 256};
        conv_lds_k<9><<<dim3(576, 2), b128, 0, stream>>>(a0, a1, a0, 256);
    }
    // 6. deviation branch (PART overlays ws0: SCH1 consumed, deep not yet written)
    rowsum_k<<<384, b256, 0, stream>>>(Bb, PART);
    dev_k<<<1, b256, 0, stream>>>(PART, sch_fc_w, sch_fc_b, out + NOUT);

    // 7. batch 1x1: fc(D)->K81(E cb0-5) ; rc(F2)->L48(E cb6-9)
    {
        ConvJob a0 = {Db, Db, 16, 0, WT + 2949120, BIAS + 1024, Eb, 96};
        ConvJob a1 = {Cb, Cb, 16, 0, WT + 2981888, BIAS + 1280, L48, 64};
        conv_lds_k<1><<<dim3(288, 2), b128, 0, stream>>>(a0, a1, a0, 128);
    }

    // 8. weight transforms, phase 2
    {
        WtxJob w0 = {ad_c1_w, ad_c1_b, nullptr, nullptr, 256, 256, 256, 256, 256, 32, 9, 0, 1536};
        WtxJob w1 = {ad_c2_w, ad_c2_b, nullptr, nullptr, 256, 256, 256, 256, 0, 16, 9, 1179648, 1792};
        WtxJob w2 = {ad_c3_w, ad_c3_b, nullptr, nullptr, 256, 256, 256, 256, 0, 16, 9, 1769472, 2048};
        WtxJob w3 = {lc1_w, lc1_b, lc1_g, lc1_beta, 256, 256, 256, 256, 48, 20, 9, 2359296, 2304};
        WtxJob w4 = {lc2_w, lc2_b, lc2_g, lc2_beta, 256, 256, 256, 256, 0, 16, 9, 3096576, 2560};
        WtxJob w5 = {lc3_w, lc3_b, nullptr, nullptr, 19, 128, 256, 256, 0, 16, 1, 3686400, 2816};
        wtx_multi_k<<<dim3(4610, 6), b256, 0, stream>>>(w0, w1, w2, w3, w4, w5, WT, BIAS);
    }

    // 9. softmax + propagation
    softmax81_k<<<72, b256, 0, stream>>>(Eb);
    xform_nhwc_k<<<2600, b256, 0, stream>>>(f1_deep, ws0);
    prop_k<<<2377, b256, 0, stream>>>(ws0, Eb, Fb);

    // 10. AdaptNet
    {
        ConvJob a = {Cb, Fb, 16, 16, WT, BIAS + 1536, Bb, 256};
        conv_lds_k<9><<<dim3(576, 1), b128, 0, stream>>>(a, a, a, 256);
    }
    {
        ConvJob a = {Bb, Bb, 16, 0, WT + 1179648, BIAS + 1792, Db, 256};
        conv_lds_k<9><<<dim3(576, 1), b128, 0, stream>>>(a, a, a, 256);
    }
    {
        ConvJob a = {Db, Db, 16, 0, WT + 1769472, BIAS + 2048, Fb, 256};
        conv_lds_k<9><<<dim3(576, 1), b128, 0, stream>>>(a, a, a, 256);
    }
    // 11. last_conv (lc1: KBtot = 16 + 4 = 20 -> nsteps 10, even)
    {
        ConvJob a = {Fb, L48, 16, 4, WT + 2359296, BIAS + 2304, Bb, 256};
        conv_lds_k<9><<<dim3(576, 1), b128, 0, stream>>>(a, a, a, 256);
    }
    {
        ConvJob a = {Bb, Bb, 16, 0, WT + 3096576, BIAS + 2560, Db, 256};
        conv_lds_k<9><<<dim3(576, 1), b128, 0, stream>>>(a, a, a, 256);
    }
    {
        ConvJob a = {Db, Db, 16, 0, WT + 3686400, BIAS + 2816, Cb, 32};
        conv_lds_k<1><<<dim3(288, 1), b128, 0, stream>>>(a, a, a, 128);
    }

    // 12. upsample
    upsample_k<<<(NOUT + 255) / 256, b256, 0, stream>>>(Cb, out);
}

// Round 10
// 489.595 us; speedup vs baseline: 1.6620x; 1.6620x over previous
//
#include <hip/hip_runtime.h>
#include <math.h>

#define HWIMG 18432          // 96*192
#define W2 194               // padded width, pad=1
#define H2 98
#define NPX1 (H2 * W2)       // 19012 padded pixels, pad=1
#define W4 200               // padded width, pad=4
#define H4 104
#define NPX4 (H4 * W4)       // 20800 padded pixels, pad=4
#define NOUT (19 * 384 * 768)

typedef short bf16x8 __attribute__((ext_vector_type(8)));
typedef float f32x16 __attribute__((ext_vector_type(16)));

__device__ __forceinline__ ushort bf16r(float f) {
    union { float f; unsigned u; } a; a.f = f;
    unsigned u = a.u;
    return (ushort)((u + 0x7fffu + ((u >> 16) & 1u)) >> 16);
}
__device__ __forceinline__ float b2f(ushort u) {
    union { unsigned i; float f; } a; a.i = ((unsigned)u) << 16;
    return a.f;
}
__device__ __forceinline__ bf16x8 ld8(const ushort* p) {
    return *reinterpret_cast<const bf16x8*>(p);
}

// async global->LDS, 16B per lane. LDS dest: wave-uniform base + lane*16.
__device__ __forceinline__ void gld16(const ushort* g, ushort* l) {
    __builtin_amdgcn_global_load_lds(
        (const __attribute__((address_space(1))) unsigned int*)g,
        (__attribute__((address_space(3))) unsigned int*)l, 16, 0, 0);
}

#define MF32(a, b, c) __builtin_amdgcn_mfma_f32_32x32x16_bf16(a, b, c, 0, 0, 0)

// ===========================================================================
// Tiled activation layout: act[cb][px][c16]  (cb = ch/16, px in padded pad=1
// image, c16 = ch%16). Weights: wt[kb][tap][ocp][16].
// ===========================================================================

// NCHW f32 -> tiled bf16 (full padded range, borders zeroed). optional src-src2.
__global__ __launch_bounds__(256) void xform_t_k(const float* __restrict__ src,
                                                 const float* __restrict__ src2,
                                                 ushort* __restrict__ dst)
{
    const int px = blockIdx.x * 32 + (threadIdx.x & 31);
    const int c8 = (blockIdx.y * 8 + (threadIdx.x >> 5)) * 8;
    if (px >= NPX1) return;
    const int yP = px / W2, xP = px % W2;
    const int y = yP - 1, x = xP - 1;
    ushort v[8];
    if (y >= 0 && y < 96 && x >= 0 && x < 192) {
        const int p = y * 192 + x;
#pragma unroll
        for (int j = 0; j < 8; ++j) {
            float f = src[(size_t)(c8 + j) * HWIMG + p];
            if (src2) f -= src2[(size_t)(c8 + j) * HWIMG + p];
            v[j] = bf16r(f);
        }
    } else {
#pragma unroll
        for (int j = 0; j < 8; ++j) v[j] = 0;
    }
    *reinterpret_cast<uint4*>(dst + ((size_t)(c8 >> 4) * NPX1 + px) * 16 + (c8 & 15))
        = *reinterpret_cast<uint4*>(v);
}

// NCHW f32 -> padded NHWC bf16 (pad=4), for the propagation input only.
__global__ __launch_bounds__(256) void xform_nhwc_k(const float* __restrict__ src,
                                                    ushort* __restrict__ dst)
{
    const int px = blockIdx.x * 8 + (threadIdx.x >> 5);
    const int c8 = (threadIdx.x & 31) * 8;
    if (px >= NPX4) return;
    const int yP = px / W4, xP = px % W4;
    const int y = yP - 4, x = xP - 4;
    ushort v[8];
    if (y >= 0 && y < 96 && x >= 0 && x < 192) {
        const int p = y * 192 + x;
#pragma unroll
        for (int j = 0; j < 8; ++j) v[j] = bf16r(src[(size_t)(c8 + j) * HWIMG + p]);
    } else {
#pragma unroll
        for (int j = 0; j < 8; ++j) v[j] = 0;
    }
    *reinterpret_cast<uint4*>(dst + (size_t)px * 256 + c8) = *reinterpret_cast<uint4*>(v);
}

// Zero pad=1 border pixels of three 16-cb tiled buffers.
__global__ __launch_bounds__(256) void borderzero3_k(ushort* __restrict__ b0,
                                                     ushort* __restrict__ b1,
                                                     ushort* __restrict__ b2)
{
    ushort* buf = (blockIdx.y == 0) ? b0 : ((blockIdx.y == 1) ? b1 : b2);
    const int idx = blockIdx.x * 256 + threadIdx.x;
    if (idx >= 580 * 16) return;
    const int pi = idx % 580;
    const int cb = idx / 580;
    int pp;
    if (pi < 194) pp = pi;
    else if (pi < 388) pp = 97 * 194 + (pi - 194);
    else if (pi < 484) pp = (pi - 388 + 1) * 194;
    else pp = (pi - 484 + 1) * 194 + 193;
    uint4 z = {0, 0, 0, 0};
    ushort* p = buf + ((size_t)cb * NPX1 + pp) * 16;
    *reinterpret_cast<uint4*>(p) = z;
    *reinterpret_cast<uint4*>(p + 8) = z;
}

// ---------------------------------------------------------------------------
// Batched weight transform: OIHW f32 -> wt[kb][tap][ocp][16] bf16 + bias f32.
// ---------------------------------------------------------------------------
struct WtxJob {
    const float* w; const float* b; const float* g; const float* beta;
    int CoutR, Coutp, CinR0, kb0e, CinR1, KBt, ntaps, wtoff, biasoff;
};

__global__ __launch_bounds__(256) void wtx_multi_k(WtxJob J0, WtxJob J1, WtxJob J2,
                                                   WtxJob J3, WtxJob J4, WtxJob J5,
                                                   ushort* __restrict__ wt,
                                                   float* __restrict__ biasout)
{
    WtxJob J = J0;
    switch (blockIdx.y) {
        case 1: J = J1; break; case 2: J = J2; break; case 3: J = J3; break;
        case 4: J = J4; break; case 5: J = J5; break; default: break;
    }
    const int idx = blockIdx.x * 256 + threadIdx.x;
    const int total = J.ntaps * J.KBt * J.Coutp * 16;
    const int CinT = J.CinR0 + J.CinR1;
    if (idx < total) {
        const int c16 = idx & 15;
        const int oc = (idx >> 4) % J.Coutp;
        const int r2 = idx / (16 * J.Coutp);
        const int tap = r2 % J.ntaps;
        const int kbt = r2 / J.ntaps;
        const int k = kbt * 16 + c16;
        float val = 0.f;
        if (oc < J.CoutR) {
            int cit = -1;
            if (k < J.kb0e) { if (k < J.CinR0) cit = k; }
            else { const int k1 = k - J.kb0e; if (k1 < J.CinR1) cit = J.CinR0 + k1; }
            if (cit >= 0) {
                val = J.w[((size_t)oc * CinT + cit) * J.ntaps + tap];
                if (J.g) val *= J.g[oc];
            }
        }
        wt[J.wtoff + idx] = bf16r(val);
    } else if (idx < total + J.Coutp) {
        const int oc = idx - total;
        float v = 0.f;
        if (oc < J.CoutR) {
            v = J.b ? J.b[oc] : 0.f;
            if (J.g) v = v * J.g[oc] + J.beta[oc];
        }
        biasout[J.biasoff + oc] = v;
    }
}

// ---------------------------------------------------------------------------
// LDS-staged implicit-GEMM conv, MFMA 32x32x16 (K=16 -> one cb per K-step),
// STATIC double-buffered at r8's total LDS (53.8KB -> 3 blocks/CU kept):
//   stage(next, S^1) -> sched_barrier -> compute(cur, S) -> syncthreads
// so the barrier's vmcnt(0) drain waits on loads issued a full compute phase
// earlier (T3 minimum 2-phase, correct ordering). Linear LDS, no swizzle:
// every ds_read_b128 wave-op covers a contiguous 1KB range.
// Block = 128 thr = 2 waves (wm = px row); tile 128px x 64oc; wave 64px x 64oc
// as 2x2 fragments of 32x32 (acc = 4 x f32x16).
// grid.x = 144 * Coutp/64 (XCD-swizzled), grid.y = job.
// ---------------------------------------------------------------------------
struct ConvJob {
    const ushort* in0; const ushort* in1;
    int KB0, KB1;
    const ushort* wt;
    const float* bias;
    ushort* out;
    int CoutWr;            // writable channels (multiple of 32)
};

template<int NTAPS>
__device__ __forceinline__ void stage_kb(
    const ConvJob& J, int kb, char* Ab, char* Bb,
    int y0, int x0, int ocb0, int Coutp, int tid)
{
    constexpr int AROWS = (NTAPS == 9) ? 4 : 2;
    constexpr int AW = (NTAPS == 9) ? 66 : 64;
    constexpr int ASLOTS = AROWS * AW * 2;            // 16B slots (528 or 256)
    const ushort* plane = (kb < J.KB0)
        ? (J.in0 + (size_t)kb * (NPX1 * 16))
        : (J.in1 + (size_t)(kb - J.KB0) * (NPX1 * 16));
    // A-halo: linear LDS dest, linear global source
#pragma unroll
    for (int i = 0; i < (ASLOTS + 127) / 128; ++i) {
        const int f16 = i * 128 + tid;
        if ((ASLOTS % 128 == 0) || (f16 < ASLOTS)) {
            const int e = f16 >> 1;
            const int h8 = (f16 & 1) * 8;
            const int r = e / AW;
            const int xx = e - r * AW;
            const int px = (NTAPS == 9)
                ? (y0 - 1 + r) * W2 + (x0 - 1 + xx)
                : (y0 + r) * W2 + (x0 + xx);
            gld16(plane + (size_t)px * 16 + h8,
                  (ushort*)(Ab + __builtin_amdgcn_readfirstlane((f16 & ~63) * 16)));
        }
    }
    // B: region t = [64oc][16ch] = 2048B = one 128-thread round per tap
    const ushort* wsrc = J.wt + ((size_t)(kb * NTAPS) * Coutp + ocb0 + (tid >> 1)) * 16
                       + (tid & 1) * 8;
    const int wu = __builtin_amdgcn_readfirstlane((tid & ~63) * 16);
#pragma unroll
    for (int t = 0; t < NTAPS; ++t) {
        gld16(wsrc + (size_t)t * Coutp * 16, (ushort*)(Bb + t * 2048 + wu));
    }
}

template<int NTAPS>
__device__ __forceinline__ void compute_step(
    f32x16& c00, f32x16& c01, f32x16& c10, f32x16& c11,
    const char* Ab, const char* Bb, int wm, int l31, int h16)
{
    constexpr int AW = (NTAPS == 9) ? 66 : 64;
#pragma unroll
    for (int t = 0; t < NTAPS; ++t) {
        const int rowb = (NTAPS == 9) ? ((wm + t / 3) * AW + (t % 3)) : (wm * AW);
        const char* Bp = Bb + t * 2048;
        bf16x8 a0 = ld8((const ushort*)(Ab + (rowb + l31) * 32 + h16));
        bf16x8 a1 = ld8((const ushort*)(Ab + (rowb + 32 + l31) * 32 + h16));
        bf16x8 b0 = ld8((const ushort*)(Bp + l31 * 32 + h16));
        bf16x8 b1 = ld8((const ushort*)(Bp + (32 + l31) * 32 + h16));
        c00 = MF32(a0, b0, c00);
        c01 = MF32(a0, b1, c01);
        c10 = MF32(a1, b0, c10);
        c11 = MF32(a1, b1, c11);
    }
}

template<int NTAPS>
__global__ __launch_bounds__(128) void conv_lds_k(ConvJob j0, ConvJob j1, ConvJob j2,
                                                  int Coutp)
{
    constexpr int AROWS = (NTAPS == 9) ? 4 : 2;
    constexpr int AW = (NTAPS == 9) ? 66 : 64;
    constexpr int APLANE = AROWS * AW * 32;           // 8448 or 4096 B
    // STATIC double buffers: total 53760B (NTAPS=9) -> 3 blocks/CU
    __shared__ __align__(128) char A0[APLANE];
    __shared__ __align__(128) char A1[APLANE];
    __shared__ __align__(128) char B0[NTAPS * 2048];
    __shared__ __align__(128) char B1[NTAPS * 2048];

    ConvJob J = j0;
    if (blockIdx.y == 1) J = j1;
    else if (blockIdx.y == 2) J = j2;

    const int nblk = gridDim.x;
    const int cpx = nblk >> 3;                        // nblk % 8 == 0
    const int sw = ((int)blockIdx.x & 7) * cpx + ((int)blockIdx.x >> 3);
    const int pt = sw % 144;
    const int ocb0 = (sw / 144) * 64;
    const int y0 = (pt / 3) * 2 + 1;
    const int x0 = (pt % 3) * 64 + 1;

    const int tid = threadIdx.x;                      // 0..127
    const int lane = tid & 63;
    const int wm = tid >> 6;                          // wave id = px row
    const int l31 = lane & 31;
    const int h16 = (lane >> 5) * 16;                 // 16B k-half within 32B row

    const int KBtot = J.KB0 + J.KB1;                  // 16, 20, or 32: even

    f32x16 c00 = {}, c01 = {}, c10 = {}, c11 = {};

    stage_kb<NTAPS>(J, 0, A0, B0, y0, x0, ocb0, Coutp, tid);
    __syncthreads();

    for (int s = 0; s < KBtot; s += 2) {
        // phase 1: stage kb s+1 into S1 while computing kb s from S0
        stage_kb<NTAPS>(J, s + 1, A1, B1, y0, x0, ocb0, Coutp, tid);
        __builtin_amdgcn_sched_barrier(0);
        compute_step<NTAPS>(c00, c01, c10, c11, A0, B0, wm, l31, h16);
        __syncthreads();   // drains S1 loads (issued one compute phase ago)
        // phase 2: stage kb s+2 into S0 while computing kb s+1 from S1
        if (s + 2 < KBtot)
            stage_kb<NTAPS>(J, s + 2, A0, B0, y0, x0, ocb0, Coutp, tid);
        __builtin_amdgcn_sched_barrier(0);
        compute_step<NTAPS>(c00, c01, c10, c11, A1, B1, wm, l31, h16);
        __syncthreads();
    }

    // ---- epilogue: 32x32 C/D map col=lane&31 (oc), row=(r&3)+8*(r>>2)+4*(lane>>5) ----
    const int pxbase = (y0 + wm) * W2 + x0;
    const int rlo = (lane >> 5) * 4;
#pragma unroll
    for (int j = 0; j < 2; ++j) {
        if (ocb0 + j * 32 + 32 > J.CoutWr) continue;  // wave-uniform
        const int oc = ocb0 + j * 32 + l31;
        const float bs = J.bias[oc];
        const size_t obase = (size_t)(oc >> 4) * ((size_t)NPX1 * 16) + (oc & 15);
        const f32x16 v0 = j ? c01 : c00;
        const f32x16 v1 = j ? c11 : c10;
#pragma unroll
        for (int r = 0; r < 16; ++r) {
            const int rw = (r & 3) + 8 * (r >> 2) + rlo;
            J.out[obase + (size_t)(pxbase + rw) * 16] = bf16r(v0[r] + bs);
            J.out[obase + (size_t)(pxbase + 32 + rw) * 16] = bf16r(v1[r] + bs);
        }
    }
}

// ---------------------------------------------------------------------------
// Softmax over 81 channels (tiled layout), in place, interior pixels.
// ---------------------------------------------------------------------------
__global__ __launch_bounds__(256) void softmax81_k(ushort* __restrict__ t)
{
    const int p = blockIdx.x * 256 + threadIdx.x;
    if (p >= HWIMG) return;
    const int y = p / 192, x = p % 192;
    const size_t pp = (size_t)(y + 1) * W2 + (x + 1);
    float v[81];
    float m = -1e30f;
#pragma unroll
    for (int k = 0; k < 81; ++k) {
        v[k] = b2f(t[((size_t)(k >> 4) * NPX1 + pp) * 16 + (k & 15)]);
        m = fmaxf(m, v[k]);
    }
    float s = 0.f;
#pragma unroll
    for (int k = 0; k < 81; ++k) { v[k] = __expf(v[k] - m); s += v[k]; }
    const float inv = 1.f / s;
#pragma unroll
    for (int k = 0; k < 81; ++k)
        t[((size_t)(k >> 4) * NPX1 + pp) * 16 + (k & 15)] = bf16r(v[k] * inv);
}

// ---------------------------------------------------------------------------
// Propagation: out[px][c] = sum_k deep[y+dy][x+dx][c] * ker[px][k]
// deep: pad4 NHWC bf16; ker: tiled (6 cb used); out: tiled, FULL write.
// ---------------------------------------------------------------------------
__global__ __launch_bounds__(256) void prop_k(const ushort* __restrict__ deep,
                                              const ushort* __restrict__ ker,
                                              ushort* __restrict__ out)
{
    __shared__ float kl[8][81];
    const int pxb = blockIdx.x * 8;
    const int t = threadIdx.x;
    for (int i = t; i < 8 * 81; i += 256) {
        const int pp = pxb + i / 81, k = i % 81;
        float kv = 0.f;
        if (pp < NPX1) {
            const int yP = pp / W2, xP = pp % W2;
            if (yP >= 1 && yP <= 96 && xP >= 1 && xP <= 192)
                kv = b2f(ker[((size_t)(k >> 4) * NPX1 + pp) * 16 + (k & 15)]);
        }
        kl[i / 81][k] = kv;
    }
    __syncthreads();
    const int pi = t >> 5;
    const int c8 = (t & 31) * 8;
    const int pp = pxb + pi;
    if (pp >= NPX1) return;
    const int yP = pp / W2, xP = pp % W2;
    ushort* op = out + ((size_t)(c8 >> 4) * NPX1 + pp) * 16 + (c8 & 15);
    if (yP < 1 || yP > 96 || xP < 1 || xP > 192) {
        uint4 z = {0, 0, 0, 0};
        *reinterpret_cast<uint4*>(op) = z;
        return;
    }
    const int y = yP - 1, x = xP - 1;
    float acc[8];
#pragma unroll
    for (int j = 0; j < 8; ++j) acc[j] = 0.f;
    const ushort* dbase = deep + ((size_t)(y + 4) * W4 + (x + 4)) * 256 + c8;
#pragma unroll
    for (int k = 0; k < 81; ++k) {
        const int dy = k / 9 - 4, dx = k % 9 - 4;
        const float kv = kl[pi][k];
        bf16x8 d = ld8(dbase + (ptrdiff_t)(dy * W4 + dx) * 256);
#pragma unroll
        for (int j = 0; j < 8; ++j) acc[j] += b2f((ushort)d[j]) * kv;
    }
    ushort v[8];
#pragma unroll
    for (int j = 0; j < 8; ++j) v[j] = bf16r(acc[j]);
    *reinterpret_cast<uint4*>(op) = *reinterpret_cast<uint4*>(v);
}

// ---------------------------------------------------------------------------
// Per-row-chunk channel sums (tiled input): partial[(y*4+bx)][c], 48 px each
// ---------------------------------------------------------------------------
__global__ __launch_bounds__(256) void rowsum_k(const ushort* __restrict__ t,
                                                float* __restrict__ partial)
{
    const int y = blockIdx.x >> 2;
    const int bx = blockIdx.x & 3;
    const int c = threadIdx.x;
    const size_t base = ((size_t)(c >> 4) * NPX1 + (size_t)(y + 1) * W2 + 1 + bx * 48) * 16
                      + (c & 15);
    float s = 0.f;
    for (int x = 0; x < 48; ++x) s += b2f(t[base + (size_t)x * 16]);
    partial[(size_t)blockIdx.x * 256 + c] = s;
}

__global__ __launch_bounds__(256) void dev_k(const float* __restrict__ partial,
                                             const float* __restrict__ fcw,
                                             const float* __restrict__ fcb,
                                             float* __restrict__ o)
{
    __shared__ float buf[256];
    const int c = threadIdx.x;
    float s = 0.f;
    for (int i = 0; i < 384; ++i) s += partial[(size_t)i * 256 + c];
    buf[c] = s * fcw[c];
    __syncthreads();
    for (int st = 128; st > 0; st >>= 1) {
        if (c < st) buf[c] += buf[c + st];
        __syncthreads();
    }
    if (c == 0) o[0] = buf[0] * (1.f / (float)HWIMG) + fcb[0];
}

// ---------------------------------------------------------------------------
// 4x bilinear upsample from tiled bf16 (19 ch used) -> f32 NCHW
// ---------------------------------------------------------------------------
__global__ __launch_bounds__(256) void upsample_k(const ushort* __restrict__ in,
                                                  float* __restrict__ outp)
{
    const int idx = blockIdx.x * 256 + threadIdx.x;
    if (idx >= NOUT) return;
    const int ox = idx % 768;
    const int t = idx / 768;
    const int oy = t % 384;
    const int c = t / 384;

    const float fx = (ox + 0.5f) * 0.25f - 0.5f;
    const float fy = (oy + 0.5f) * 0.25f - 0.5f;
    const int x0 = (int)floorf(fx);
    const int y0 = (int)floorf(fy);
    const float wx = fx - (float)x0;
    const float wy = fy - (float)y0;
    const int x0c = min(max(x0, 0), 191), x1c = min(max(x0 + 1, 0), 191);
    const int y0c = min(max(y0, 0), 95), y1c = min(max(y0 + 1, 0), 95);

    const size_t cb = (size_t)(c >> 4) * NPX1;
    const int c16 = c & 15;
    const float v00 = b2f(in[(cb + (size_t)(y0c + 1) * W2 + (x0c + 1)) * 16 + c16]);
    const float v01 = b2f(in[(cb + (size_t)(y0c + 1) * W2 + (x1c + 1)) * 16 + c16]);
    const float v10 = b2f(in[(cb + (size_t)(y1c + 1) * W2 + (x0c + 1)) * 16 + c16]);
    const float v11 = b2f(in[(cb + (size_t)(y1c + 1) * W2 + (x1c + 1)) * 16 + c16]);
    outp[idx] = (1.f - wy) * ((1.f - wx) * v00 + wx * v01)
              + wy * ((1.f - wx) * v10 + wx * v11);
}

// ---------------------------------------------------------------------------
extern "C" void kernel_launch(void* const* d_in, const int* in_sizes, int n_in,
                              void* d_out, int out_size, void* d_ws, size_t ws_size,
                              hipStream_t stream)
{
    const float* f1_deep = (const float*)d_in[0];
    const float* f1_low  = (const float*)d_in[1];
    const float* f2_low  = (const float*)d_in[2];
    const float* wp_c1_w = (const float*)d_in[3];
    const float* wp_c1_b = (const float*)d_in[4];
    const float* wp_c2_w = (const float*)d_in[5];
    const float* wp_c2_b = (const float*)d_in[6];
    const float* wp_fc_w = (const float*)d_in[7];
    const float* wp_fc_b = (const float*)d_in[8];
    const float* sch_c1_w = (const float*)d_in[9];
    const float* sch_c2_w = (const float*)d_in[11];
    const float* sch_c2_b = (const float*)d_in[12];
    const float* sch_fc_w = (const float*)d_in[13];
    const float* sch_fc_b = (const float*)d_in[14];
    const float* ad_c1_w = (const float*)d_in[15];
    const float* ad_c1_b = (const float*)d_in[16];
    const float* ad_c2_w = (const float*)d_in[17];
    const float* ad_c2_b = (const float*)d_in[18];
    const float* ad_c3_w = (const float*)d_in[19];
    const float* ad_c3_b = (const float*)d_in[20];
    const float* rc_w    = (const float*)d_in[21];
    const float* rc_b    = (const float*)d_in[22];
    const float* rc_g    = (const float*)d_in[23];
    const float* rc_beta = (const float*)d_in[24];
    const float* lc1_w   = (const float*)d_in[25];
    const float* lc1_b   = (const float*)d_in[26];
    const float* lc1_g   = (const float*)d_in[27];
    const float* lc1_beta= (const float*)d_in[28];
    const float* lc2_w   = (const float*)d_in[29];
    const float* lc2_b   = (const float*)d_in[30];
    const float* lc2_g   = (const float*)d_in[31];
    const float* lc2_beta= (const float*)d_in[32];
    const float* lc3_w   = (const float*)d_in[33];
    const float* lc3_b   = (const float*)d_in[34];

    float* out = (float*)d_out;
    ushort* ws0 = (ushort*)d_ws;

    const size_t CBBe  = (size_t)NPX1 * 256;   // elems of one 16-cb tiled buffer
    const size_t BUF0e = (size_t)NPX4 * 256;   // pad4 NHWC deep buffer elems

    ushort* Bb = ws0 + BUF0e;            // slot B
    ushort* Cb = Bb + CBBe;              // slot C
    ushort* Db = Cb + CBBe;              // slot D
    ushort* Eb = Db + CBBe;              // slot E
    ushort* Fb = Eb + CBBe;              // slot F
    ushort* WT = Fb + CBBe;              // weights: 3,719,168 elems
    float* BIAS = (float*)(WT + 3719168);
    float* PART = (float*)ws0;           // lives only step 6 (ws0 free there)
    ushort* L48 = Eb + 6 * (size_t)NPX1 * 16;   // cb6-9 of slot E

    const dim3 b256(256), b128(128);

    // 1. input transforms (full writes incl. zero borders)
    xform_t_k<<<dim3(595, 4), b256, 0, stream>>>(f1_low, nullptr, Bb);
    xform_t_k<<<dim3(595, 4), b256, 0, stream>>>(f2_low, nullptr, Cb);
    xform_t_k<<<dim3(595, 4), b256, 0, stream>>>(f1_low, f2_low, Db);
    // 2. zero borders of conv-output slots that get halo-read (stay zero after)
    borderzero3_k<<<dim3(37, 3), b256, 0, stream>>>(ws0, Eb, Fb);

    // 3. weight transforms, phase 1
    {
        WtxJob w0 = {wp_c1_w, wp_c1_b, nullptr, nullptr, 256, 256, 256, 256, 0, 16, 9, 0, 0};
        WtxJob w1 = {sch_c1_w, nullptr, nullptr, nullptr, 256, 256, 256, 256, 0, 16, 9, 589824, 256};
        WtxJob w2 = {wp_c2_w, wp_c2_b, nullptr, nullptr, 256, 256, 256, 256, 256, 32, 9, 1179648, 512};
        WtxJob w3 = {sch_c2_w, sch_c2_b, nullptr, nullptr, 256, 256, 256, 256, 0, 16, 9, 2359296, 768};
        WtxJob w4 = {wp_fc_w, wp_fc_b, nullptr, nullptr, 81, 128, 256, 256, 0, 16, 1, 2949120, 1024};
        WtxJob w5 = {rc_w, rc_b, rc_g, rc_beta, 48, 128, 256, 256, 0, 16, 1, 2981888, 1280};
        wtx_multi_k<<<dim3(4610, 6), b256, 0, stream>>>(w0, w1, w2, w3, w4, w5, WT, BIAS);
    }

    // 4. batch A: wp_c1(F1)->E, wp_c1(F2)->F, sch_c1(DIFF)->SCH1(ws0)
    {
        ConvJob a0 = {Bb, Bb, 16, 0, WT, BIAS, Eb, 256};
        ConvJob a1 = {Cb, Cb, 16, 0, WT, BIAS, Fb, 256};
        ConvJob a2 = {Db, Db, 16, 0, WT + 589824, BIAS + 256, ws0, 256};
        conv_lds_k<9><<<dim3(576, 3), b128, 0, stream>>>(a0, a1, a2, 256);
    }
    // 5. batch B: wp_c2(E,F)->D ; sch_c2(SCH1)->B
    {
        ConvJob a0 = {Eb, Fb, 16, 16, WT + 1179648, BIAS + 512, Db, 256};
        ConvJob a1 = {ws0, ws0, 16, 0, WT + 2359296, BIAS + 768, Bb, 256};
        conv_lds_k<9><<<dim3(576, 2), b128, 0, stream>>>(a0, a1, a0, 256);
    }
    // 6. deviation branch (PART overlays ws0: SCH1 consumed, deep not yet written)
    rowsum_k<<<384, b256, 0, stream>>>(Bb, PART);
    dev_k<<<1, b256, 0, stream>>>(PART, sch_fc_w, sch_fc_b, out + NOUT);

    // 7. batch 1x1: fc(D)->K81(E cb0-5) ; rc(F2)->L48(E cb6-9)
    {
        ConvJob a0 = {Db, Db, 16, 0, WT + 2949120, BIAS + 1024, Eb, 96};
        ConvJob a1 = {Cb, Cb, 16, 0, WT + 2981888, BIAS + 1280, L48, 64};
        conv_lds_k<1><<<dim3(288, 2), b128, 0, stream>>>(a0, a1, a0, 128);
    }

    // 8. weight transforms, phase 2
    {
        WtxJob w0 = {ad_c1_w, ad_c1_b, nullptr, nullptr, 256, 256, 256, 256, 256, 32, 9, 0, 1536};
        WtxJob w1 = {ad_c2_w, ad_c2_b, nullptr, nullptr, 256, 256, 256, 256, 0, 16, 9, 1179648, 1792};
        WtxJob w2 = {ad_c3_w, ad_c3_b, nullptr, nullptr, 256, 256, 256, 256, 0, 16, 9, 1769472, 2048};
        WtxJob w3 = {lc1_w, lc1_b, lc1_g, lc1_beta, 256, 256, 256, 256, 48, 20, 9, 2359296, 2304};
        WtxJob w4 = {lc2_w, lc2_b, lc2_g, lc2_beta, 256, 256, 256, 256, 0, 16, 9, 3096576, 2560};
        WtxJob w5 = {lc3_w, lc3_b, nullptr, nullptr, 19, 128, 256, 256, 0, 16, 1, 3686400, 2816};
        wtx_multi_k<<<dim3(4610, 6), b256, 0, stream>>>(w0, w1, w2, w3, w4, w5, WT, BIAS);
    }

    // 9. softmax + propagation
    softmax81_k<<<72, b256, 0, stream>>>(Eb);
    xform_nhwc_k<<<2600, b256, 0, stream>>>(f1_deep, ws0);
    prop_k<<<2377, b256, 0, stream>>>(ws0, Eb, Fb);

    // 10. AdaptNet
    {
        ConvJob a = {Cb, Fb, 16, 16, WT, BIAS + 1536, Bb, 256};
        conv_lds_k<9><<<dim3(576, 1), b128, 0, stream>>>(a, a, a, 256);
    }
    {
        ConvJob a = {Bb, Bb, 16, 0, WT + 1179648, BIAS + 1792, Db, 256};
        conv_lds_k<9><<<dim3(576, 1), b128, 0, stream>>>(a, a, a, 256);
    }
    {
        ConvJob a = {Db, Db, 16, 0, WT + 1769472, BIAS + 2048, Fb, 256};
        conv_lds_k<9><<<dim3(576, 1), b128, 0, stream>>>(a, a, a, 256);
    }
    // 11. last_conv (lc1: KBtot = 16 + 4 = 20, even)
    {
        ConvJob a = {Fb, L48, 16, 4, WT + 2359296, BIAS + 2304, Bb, 256};
        conv_lds_k<9><<<dim3(576, 1), b128, 0, stream>>>(a, a, a, 256);
    }
    {
        ConvJob a = {Bb, Bb, 16, 0, WT + 3096576, BIAS + 2560, Db, 256};
        conv_lds_k<9><<<dim3(576, 1), b128, 0, stream>>>(a, a, a, 256);
    }
    {
        ConvJob a = {Db, Db, 16, 0, WT + 3686400, BIAS + 2816, Cb, 32};
        conv_lds_k<1><<<dim3(288, 1), b128, 0, stream>>>(a, a, a, 128);
    }

    // 12. upsample
    upsample_k<<<(NOUT + 255) / 256, b256, 0, stream>>>(Cb, out);
}